// Round 13
// baseline (302.976 us; speedup 1.0000x reference)
//
#include <hip/hip_runtime.h>
#include <hip/hip_bf16.h>

typedef short s16x8 __attribute__((ext_vector_type(8)));
typedef short s16x4 __attribute__((ext_vector_type(4)));
typedef float f32x4 __attribute__((ext_vector_type(4)));

#define TB 8            // batch elements per group
#define NBG 8           // groups per block; grid 1024 (3 blocks/CU resident + tail)
#define HALO 46         // gtile positions per batch (pos -2 .. 43)
#define GSTRIDE 2216    // shorts per batch in gtile (8*odd: bank-decorrelated)
#define USTRIDE 50      // floats per batch in u_s halo
#define NT 3            // stage-2 N tiles (48 cols, >=37 zero-padded; k=240 = b2 row)
#define GT_SHORTS (TB * GSTRIDE)       // 17728 shorts = 35456 B (single buffer)

__device__ __forceinline__ unsigned short f2bf(float f) {
    unsigned int u = __float_as_uint(f);
    u += 0x7fff + ((u >> 16) & 1);   // RNE
    return (unsigned short)(u >> 16);
}

// packed f32x2 -> bf16x2 (v_cvt_pk_bf16_f32, RNE)
__device__ __forceinline__ unsigned int pk_bf16(float lo, float hi) {
    float2 f; f.x = lo; f.y = hi;
    __hip_bfloat162 h = __float22bfloat162_rn(f);
    union { __hip_bfloat162 b; unsigned int u; } c;
    c.b = h;
    return c.u;
}

// (256,3): 3 blocks/CU, unified reg cap ~170/wave. Diet vs R8 (which spilled at ~190 demand):
// aW1 20->10 (16x16x16 K-trim), cf 18->0 (volatile reload/group), P2 accs 20->12 (two-pass).
// Guards: WRITE_SIZE == 10.24 MB (spill detector), OccupancyPercent ~30.
__global__ __launch_bounds__(256, 3) void lorenz96_fused(
    const float* __restrict__ u,
    const float* __restrict__ coeff,
    const float* __restrict__ W1,
    const float* __restrict__ b1,
    const float* __restrict__ W2,
    const float* __restrict__ b2,
    const float* __restrict__ W3,
    const float* __restrict__ b3,
    float* __restrict__ out)
{
    // LDS: gtile 35456 (aliases W2 staging) + u_sbuf 3200 = 38656 B -> 3 blocks/CU (116 KB/CU)
    __shared__ __align__(16) unsigned short gtile[GT_SHORTS];
    __shared__ __align__(16) float u_sbuf[2][TB * USTRIDE];   // u_s[b][k] = u[b][(k+36)%40]

    unsigned short* B_lds = gtile;   // alias: consumed into regs before gtile is written

    const int t    = threadIdx.x;
    const int lane = t & 63;
    const int wave = t >> 6;
    const int quad = lane >> 4;
    const int l15  = lane & 15;

    const int b0_block = blockIdx.x * (TB * NBG);

    // ---------- init 0a: W2 staging, pre-swizzled; k=240 carries b2 (bias row, B supplies 1.0) ----------
    // W2eff[o][k = tap*48 + c] = W2[o][c][tap]; lane holds [o = nt*16+l15][k = ks*32+quad*8+j]
    for (int g = t; g < NT * 8 * 64; g += 256) {
        int lg = g & 63;
        int ks = (g >> 6) & 7;
        int nt = g >> 9;
        int o  = nt * 16 + (lg & 15);
        int kb = ks * 32 + (lg >> 4) * 8;
        s16x8 pack = {0, 0, 0, 0, 0, 0, 0, 0};
        #pragma unroll
        for (int j = 0; j < 8; ++j) {
            int k = kb + j;
            if (o < 37) {
                if (k < 240) {
                    int c = k % 48, tap = k / 48;
                    pack[j] = (short)f2bf(W2[o * 240 + c * 5 + tap]);
                } else if (k == 240) {
                    pack[j] = (short)f2bf(b2[o]);
                }
            }
        }
        *(s16x8*)&B_lds[g * 8] = pack;
    }

    // ---------- init 0b: conv1 A-fragments, K=16 (16x16x16bf16_1k; taps k0-4, bias k5) ----------
    // A layout: lane holds A[m=l15][k = quad*4 + j], j=0..3. quad0: W1 taps 0-3; quad1: tap4, b1, 0, 0.
    // tiles: T0=ch0-15, T1=ch16-31, T2=ch32-47, T3 rows8-15=ch48-55, T4=ch56-71.
    // GLU in-lane: T1 rows8-15 x T3 rows8-15; T2 x T4 (same quad,reg in C layout).
    s16x4 aW1[5];
    {
        int chs[5];
        chs[0] = l15; chs[1] = 16 + l15; chs[2] = 32 + l15;
        chs[3] = (l15 >= 8) ? 40 + l15 : -1;
        chs[4] = 56 + l15;
        #pragma unroll
        for (int mt = 0; mt < 5; ++mt) {
            s16x4 a = {0, 0, 0, 0};
            int ch = chs[mt];
            if (ch >= 0) {
                if (quad == 0) {
                    #pragma unroll
                    for (int j = 0; j < 4; ++j) a[j] = (short)f2bf(W1[ch * 5 + j]);
                } else if (quad == 1) {
                    a[0] = (short)f2bf(W1[ch * 5 + 4]);
                    a[1] = (short)f2bf(b1[ch]);   // bias; B supplies 1.0 at k=5
                }
            }
            aW1[mt] = a;
        }
    }

    // ---------- init 0c: epilogue constants (b2 folded into GEMM; only W3 left) ----------
    float w3v[NT][4];
    #pragma unroll
    for (int nt = 0; nt < NT; ++nt)
        #pragma unroll
        for (int r = 0; r < 4; ++r) {
            int o = nt * 16 + quad * 4 + r;
            w3v[nt][r] = (o < 37) ? W3[o] : 0.f;
        }
    const float b3v = b3[0];

    // cf NOT register-resident: reloaded per group through volatile view (SMEM/VMEM pipe is idle)
    const volatile float* coeffv = (const volatile float*)coeff;

    // stage-2 A-fragments + poly regs (declared before lambdas)
    s16x8 aW2[NT][8];
    float pv_q = 0.f, pv_4 = 0.f;   // poly for tile i=quad row / tile i=4 row (quad0)

    // ---------- helpers ----------
    auto prestage_u = [&](int grp) {   // stage u halo for group grp into u_sbuf[grp&1]
        for (int idx = t; idx < TB * USTRIDE; idx += 256) {
            int b = idx / USTRIDE, k = idx - b * USTRIDE;
            int gi = k + 36; gi -= (gi >= 40) ? 40 : 0; gi -= (gi >= 40) ? 40 : 0;
            u_sbuf[grp & 1][idx] = u[(size_t)(b0_block + grp * TB + b) * 40 + gi];
        }
    };

    auto poly1 = [&](const float* u_s, const float* c, int m) -> float {
        int p = m >> 3, b = m & 7;
        const float* us = &u_s[b * USTRIDE + p];
        float um2 = us[2], um1 = us[3], u0 = us[4], up1 = us[5], up2 = us[6];
        return c[0] + c[1]*um2 + c[2]*um1 + c[3]*u0 + c[4]*up1 + c[5]*up2
             + c[6]*um2*um2 + c[7]*um1*um1 + c[8]*u0*u0 + c[9]*up1*up1 + c[10]*up2*up2
             + c[11]*um2*um1 + c[12]*um1*u0 + c[13]*u0*up1 + c[14]*up1*up2
             + c[15]*um2*u0 + c[16]*um1*up1 + c[17]*u0*up2;
    };

    auto poly = [&](int grp) {         // fill pv_q / pv_4 (transient cf regs, freed after)
        float c[18];
        #pragma unroll
        for (int i = 0; i < 18; ++i) c[i] = coeffv[i];
        const float* u_s = u_sbuf[grp & 1];
        pv_q = poly1(u_s, c, (wave + 4 * quad) * 16 + l15);
        pv_4 = poly1(u_s, c, (wave + 16) * 16 + l15);
    };

    auto phase2 = [&](int grp) {       // conv1 via 16x16x16 MFMA + GLU -> gtile (two-pass epilogue)
        const float* u_s = u_sbuf[grp & 1];
        #pragma unroll
        for (int i = 0; i < 6; ++i) {
            const int ct = wave + 4 * i;               // col-tiles 0..22 live (cols 0..367)
            if (ct > 22) continue;                      // only wave3,i=5: cols 368+ are pad
            const int col = ct * 16 + l15;
            const int b = col & 7, h = col >> 3;        // h <= 45 < HALO always
            s16x4 bU = {0, 0, 0, 0};
            if (quad == 0) {
                const float* us = &u_s[b * USTRIDE + h];   // taps u[(h-4+j)%40], j=0..4
                union { s16x4 v; unsigned int w[2]; } bu;
                bu.w[0] = pk_bf16(us[0], us[1]);
                bu.w[1] = pk_bf16(us[2], us[3]);
                bU = bu.v;
            } else if (quad == 1) {
                const float* us = &u_s[b * USTRIDE + h];
                union { s16x4 v; unsigned int w[2]; } bu;
                bu.w[0] = pk_bf16(us[4], 1.0f);            // tap4 + bias-slot 1.0 (k=4,5)
                bu.w[1] = 0;
                bU = bu.v;
            }
            unsigned short* gp = &gtile[b * GSTRIDE + h * 48 + quad * 4];
            {   // pass A: T0, T1 (gated by T3 on rows 8-15)
                f32x4 a0 = {0.f,0.f,0.f,0.f}, a1 = a0, a3 = a0;
                a0 = __builtin_amdgcn_mfma_f32_16x16x16bf16_1k(aW1[0], bU, a0, 0, 0, 0);
                a1 = __builtin_amdgcn_mfma_f32_16x16x16bf16_1k(aW1[1], bU, a1, 0, 0, 0);
                a3 = __builtin_amdgcn_mfma_f32_16x16x16bf16_1k(aW1[3], bU, a3, 0, 0, 0);
                float v0[4], v1[4];
                #pragma unroll
                for (int r = 0; r < 4; ++r) {
                    v0[r] = fmaxf(a0[r], 0.f);
                    v1[r] = fmaxf(a1[r], 0.f);
                    if (quad >= 2) v1[r] *= fmaxf(a3[r], 0.f);      // ch24-31 gate
                }
                union { s16x4 v; unsigned int w[2]; } w0, w1;
                w0.w[0] = pk_bf16(v0[0], v0[1]); w0.w[1] = pk_bf16(v0[2], v0[3]);
                w1.w[0] = pk_bf16(v1[0], v1[1]); w1.w[1] = pk_bf16(v1[2], v1[3]);
                *(s16x4*)(gp)      = w0.v;
                *(s16x4*)(gp + 16) = w1.v;
            }
            {   // pass B: T2 gated by T4
                f32x4 a2 = {0.f,0.f,0.f,0.f}, a4 = a2;
                a2 = __builtin_amdgcn_mfma_f32_16x16x16bf16_1k(aW1[2], bU, a2, 0, 0, 0);
                a4 = __builtin_amdgcn_mfma_f32_16x16x16bf16_1k(aW1[4], bU, a4, 0, 0, 0);
                float v2[4];
                #pragma unroll
                for (int r = 0; r < 4; ++r)
                    v2[r] = fmaxf(a2[r], 0.f) * fmaxf(a4[r], 0.f);  // ch32-47 gate
                union { s16x4 v; unsigned int w[2]; } w2;
                w2.w[0] = pk_bf16(v2[0], v2[1]); w2.w[1] = pk_bf16(v2[2], v2[3]);
                *(s16x4*)(gp + 32) = w2.v;
            }
        }
    };

    // P3 tile i: stage-2 GEMM (16x16x32) + fused relu/W3 epilogue -> out.
    // Store by quad i (i<4, pv_q) or quad 0 (i=4, pv_4) -- poly value lives in that quad's reg.
    auto p3_tile = [&](int i, int b0) {
        const int mt = wave + 4 * i;               // 20 M-tiles (320 G-rows)
        const int m  = mt * 16 + l15;
        const int p  = m >> 3, b = m & 7;
        const unsigned short* gbase = &gtile[b * GSTRIDE + p * 48 + quad * 8];
        f32x4 c0 = {0.f,0.f,0.f,0.f}, c1 = c0, c2 = c0;
        #pragma unroll
        for (int ks = 0; ks < 8; ++ks) {           // streamed bg: small transient footprint
            s16x8 bgk = *(const s16x8*)(gbase + ks * 32);
            if (ks == 7 && quad == 2) bgk[0] = (short)0x3F80;   // bias row k=240 reads 1.0
            c0 = __builtin_amdgcn_mfma_f32_16x16x32_bf16(aW2[0][ks], bgk, c0, 0, 0, 0);
            c1 = __builtin_amdgcn_mfma_f32_16x16x32_bf16(aW2[1][ks], bgk, c1, 0, 0, 0);
            c2 = __builtin_amdgcn_mfma_f32_16x16x32_bf16(aW2[2][ks], bgk, c2, 0, 0, 0);
        }
        float s = 0.f;
        #pragma unroll
        for (int r = 0; r < 4; ++r) {
            s += fmaxf(c0[r], 0.f) * w3v[0][r];
            s += fmaxf(c1[r], 0.f) * w3v[1][r];
            s += fmaxf(c2[r], 0.f) * w3v[2][r];
        }
        s += __shfl_xor(s, 16, 64);                // sum the 4 quads
        s += __shfl_xor(s, 32, 64);
        const float pv = (i < 4) ? pv_q : pv_4;
        const bool  st = (i < 4) ? (quad == i) : (quad == 0);
        if (st) {
            out[(size_t)(b0 + (l15 & 7)) * 40 + 2 * mt + (l15 >> 3)] = s + b3v + pv;
        }
    };

    // ---------- prologue ----------
    prestage_u(0);
    __syncthreads();   // B1: B_lds + u_sbuf[0] ready

    #pragma unroll
    for (int nt = 0; nt < NT; ++nt)
        #pragma unroll
        for (int ks = 0; ks < 8; ++ks)
            aW2[nt][ks] = *(const s16x8*)&B_lds[((nt * 8 + ks) * 64 + lane) * 8];

    poly(0);           // pv regs for group 0
    __syncthreads();   // B2: aW2 fragment reads done -> safe to overwrite gtile

    phase2(0);
    prestage_u(1);
    __syncthreads();   // B3: gtile ready

    // ---------- main loop: 2 barriers/group; 3 blocks/CU interleave across the barriers ----------
    for (int g = 0; g < NBG; ++g) {
        const int b0 = b0_block + g * TB;

        #pragma unroll
        for (int i = 0; i < 5; ++i) p3_tile(i, b0);   // consumes gtile + pv (group g)

        if (g + 1 < NBG) {
            __syncthreads();             // barrier A: P3 reads of gtile done
            poly(g + 1);                 // overwrites pv regs for group g+1
            phase2(g + 1);               // overwrites gtile
            if (g + 2 < NBG) prestage_u(g + 2);
            __syncthreads();             // barrier B: gtile ready
        }
    }
}

extern "C" void kernel_launch(void* const* d_in, const int* in_sizes, int n_in,
                              void* d_out, int out_size, void* d_ws, size_t ws_size,
                              hipStream_t stream) {
    // inputs: 0=t(unused), 1=u, 2=coeff, 3=W1, 4=b1, 5=W2, 6=b2, 7=W3, 8=b3
    const float* u     = (const float*)d_in[1];
    const float* coeff = (const float*)d_in[2];
    const float* W1    = (const float*)d_in[3];
    const float* b1    = (const float*)d_in[4];
    const float* W2    = (const float*)d_in[5];
    const float* b2    = (const float*)d_in[6];
    const float* W3    = (const float*)d_in[7];
    const float* b3    = (const float*)d_in[8];
    float* out = (float*)d_out;

    const int n_batch = in_sizes[1] / 40;            // 65536
    const int grid = n_batch / (TB * NBG);           // 1024 blocks (3/CU resident + tail)
    lorenz96_fused<<<grid, 256, 0, stream>>>(u, coeff, W1, b1, W2, b2, W3, b3, out);
}